// Round 1
// baseline (1843.805 us; speedup 1.0000x reference)
//
#include <hip/hip_runtime.h>
#include <hip/hip_bf16.h>
#include <math.h>

#define MQ      1024
#define NTRAIN  200000
#define KDIM    768
#define NCLS    1000
#define CAP     1024
#define DELTA   12.0f
#define KSEL    32
#define TINV    (1.0f/0.07f)

typedef short s16x8 __attribute__((ext_vector_type(8)));
typedef float f32x4 __attribute__((ext_vector_type(4)));

__device__ __forceinline__ unsigned encf(float x){
    unsigned u = __float_as_uint(x);
    return (u & 0x80000000u) ? ~u : (u | 0x80000000u);
}
__device__ __forceinline__ float decf(unsigned e){
    unsigned u = (e & 0x80000000u) ? (e & 0x7FFFFFFFu) : ~e;
    return __uint_as_float(u);
}
__device__ __forceinline__ ushort cvt_bf16(float x){
    unsigned u = __float_as_uint(x);
    u += 0x7FFFu + ((u >> 16) & 1u);   // round-to-nearest-even
    return (ushort)(u >> 16);
}

__global__ void init_kernel(unsigned* rowMaxBits, int* counts){
    int i = blockIdx.x * blockDim.x + threadIdx.x;
    if (i < MQ){ rowMaxBits[i] = 0u; counts[i] = 0; }
}

// 128x128 tile bf16 MFMA GEMM with fused running-max + candidate collection.
// grid = (8 M-tiles, 1563 N-tiles); x fastest => all 8 M-tiles of one N-tile
// are dispatch-adjacent -> bank column tile shared via L2/L3.
__launch_bounds__(256)
__global__ void gemm_collect_kernel(const float* __restrict__ Aq,
                                    const float* __restrict__ Bt,
                                    unsigned* __restrict__ rowMaxBits,
                                    int* __restrict__ counts,
                                    int* __restrict__ cands){
    const int m0 = blockIdx.x * 128;
    const int n0 = blockIdx.y * 128;
    const int tid  = threadIdx.x;
    const int lane = tid & 63;
    const int wave = tid >> 6;
    const int wm = (wave >> 1) * 64;
    const int wn = (wave & 1) * 64;

    __shared__ union {
        struct { ushort As[128][32]; ushort Bs[128][32]; } s;  // 16 KB
        float Csh[64][129];                                     // 33 KB
    } sm;

    f32x4 acc[4][4];
    #pragma unroll
    for (int i = 0; i < 4; ++i)
        #pragma unroll
        for (int j = 0; j < 4; ++j)
            acc[i][j] = (f32x4){0.f, 0.f, 0.f, 0.f};

    const int fr = lane & 15;
    const int fg = lane >> 4;

    for (int kt = 0; kt < KDIM / 32; ++kt){
        const int k0 = kt * 32;
        __syncthreads();
        // stage A,B tiles: 128 rows x 32 k fp32 -> bf16 in LDS
        #pragma unroll
        for (int i = 0; i < 4; ++i){
            int f  = tid + i * 256;       // float4 index, 0..1023
            int r  = f >> 3;              // 8 float4 per row
            int kc = (f & 7) * 4;
            float4 av = *reinterpret_cast<const float4*>(Aq + (size_t)(m0 + r) * KDIM + k0 + kc);
            ushort4 ah; ah.x = cvt_bf16(av.x); ah.y = cvt_bf16(av.y);
            ah.z = cvt_bf16(av.z); ah.w = cvt_bf16(av.w);
            *reinterpret_cast<ushort4*>(&sm.s.As[r][kc]) = ah;
            int nr = n0 + r;
            float4 bv = make_float4(0.f, 0.f, 0.f, 0.f);
            if (nr < NTRAIN)
                bv = *reinterpret_cast<const float4*>(Bt + (size_t)nr * KDIM + k0 + kc);
            ushort4 bh; bh.x = cvt_bf16(bv.x); bh.y = cvt_bf16(bv.y);
            bh.z = cvt_bf16(bv.z); bh.w = cvt_bf16(bv.w);
            *reinterpret_cast<ushort4*>(&sm.s.Bs[r][kc]) = bh;
        }
        __syncthreads();
        s16x8 af[4], bfv[4];
        #pragma unroll
        for (int i = 0; i < 4; ++i){
            af[i]  = *reinterpret_cast<const s16x8*>(&sm.s.As[wm + i * 16 + fr][fg * 8]);
            bfv[i] = *reinterpret_cast<const s16x8*>(&sm.s.Bs[wn + i * 16 + fr][fg * 8]);
        }
        #pragma unroll
        for (int i = 0; i < 4; ++i)
            #pragma unroll
            for (int j = 0; j < 4; ++j)
                acc[i][j] = __builtin_amdgcn_mfma_f32_16x16x32_bf16(af[i], bfv[j], acc[i][j], 0, 0, 0);
    }

    // epilogue: two 64-row half-tiles through LDS; per-row max + collect
    for (int half = 0; half < 2; ++half){
        __syncthreads();
        if ((wave >> 1) == half){
            #pragma unroll
            for (int i = 0; i < 4; ++i)
                #pragma unroll
                for (int j = 0; j < 4; ++j)
                    #pragma unroll
                    for (int q = 0; q < 4; ++q){
                        int rr = i * 16 + (lane >> 4) * 4 + q;   // 0..63
                        int cc = wn + j * 16 + (lane & 15);      // 0..127
                        sm.Csh[rr][cc] = acc[i][j][q];
                    }
        }
        __syncthreads();
        if (tid < 64){
            int grow = m0 + half * 64 + tid;
            float mx = -1e30f;
            #pragma unroll 4
            for (int c = 0; c < 128; ++c) mx = fmaxf(mx, sm.Csh[tid][c]);
            unsigned old = atomicMax(&rowMaxBits[grow], encf(mx));
            float gmax = fmaxf(mx, decf(old));
            float thr = gmax - DELTA;
            for (int c = 0; c < 128; ++c){
                int gcol = n0 + c;
                if (gcol < NTRAIN && sm.Csh[tid][c] >= thr){
                    int slot = atomicAdd(&counts[grow], 1);
                    if (slot < CAP) cands[(size_t)grow * CAP + slot] = gcol;
                }
            }
        }
    }
}

// one block per query row: exact fp32 rescore of candidates, top-KSEL,
// softmax, per-class accumulation, dense output write.
__launch_bounds__(256)
__global__ void rescore_output_kernel(const float* __restrict__ Aq,
                                      const float* __restrict__ Bt,
                                      const int* __restrict__ labels,
                                      const int* __restrict__ counts,
                                      const int* __restrict__ cands,
                                      float* __restrict__ out){
    const int row  = blockIdx.x;
    const int tid  = threadIdx.x;
    const int lane = tid & 63;
    const int wave = tid >> 6;

    __shared__ float q[KDIM];
    __shared__ float sv[CAP];
    __shared__ float rv[256];
    __shared__ int   ri[256];
    __shared__ float topS[KSEL];
    __shared__ int   topI[KSEL];
    __shared__ float cls[3][NCLS];

    for (int k = tid; k < KDIM; k += 256) q[k] = Aq[(size_t)row * KDIM + k];
    int m = counts[row]; if (m > CAP) m = CAP;
    __syncthreads();

    // exact fp32 sims: one wave per candidate, lane-split K
    for (int c = wave; c < m; c += 4){
        int idx = cands[(size_t)row * CAP + c];
        const float* b = Bt + (size_t)idx * KDIM;
        float s = 0.f;
        #pragma unroll
        for (int u = 0; u < 12; ++u){
            int k = lane * 12 + u;
            s += q[k] * b[k];
        }
        #pragma unroll
        for (int off = 32; off; off >>= 1) s += __shfl_down(s, off);
        if (lane == 0) sv[c] = s;
    }
    __syncthreads();

    // iterative argmax extraction of top-KSEL
    int msel = m < KSEL ? m : KSEL;
    for (int j = 0; j < msel; ++j){
        float bs = -1e30f; int bi = 0x7FFFFFFF;
        for (int c = tid; c < m; c += 256){
            float v = sv[c];
            if (v > bs){ bs = v; bi = c; }
        }
        rv[tid] = bs; ri[tid] = bi;
        __syncthreads();
        for (int st = 128; st; st >>= 1){
            if (tid < st){
                if (rv[tid + st] > rv[tid] ||
                    (rv[tid + st] == rv[tid] && ri[tid + st] < ri[tid])){
                    rv[tid] = rv[tid + st]; ri[tid] = ri[tid + st];
                }
            }
            __syncthreads();
        }
        if (tid == 0){
            topS[j] = rv[0];
            topI[j] = cands[(size_t)row * CAP + ri[0]];
            sv[ri[0]] = -1e30f;
        }
        __syncthreads();
    }

    for (int i = tid; i < 3 * NCLS; i += 256) (&cls[0][0])[i] = 0.f;
    __syncthreads();

    if (tid == 0){
        float s0 = topS[0];
        float e[KSEL];
        float Z = 0.f;
        for (int j = 0; j < msel; ++j){ e[j] = __expf((topS[j] - s0) * TINV); Z += e[j]; }
        float inv = 1.f / Z;
        for (int j = 0; j < msel; ++j){
            int lb = labels[topI[j]];
            float w = e[j] * inv;
            if (j < 10) cls[0][lb] += w;
            if (j < 50) cls[1][lb] += w;
            cls[2][lb] += w;
        }
    }
    __syncthreads();

    for (int c = tid; c < NCLS; c += 256){
        out[(size_t)row * NCLS + c]                       = cls[0][c];
        out[(size_t)MQ * NCLS + (size_t)row * NCLS + c]   = cls[1][c];
        out[(size_t)2 * MQ * NCLS + (size_t)row * NCLS + c] = cls[2][c];
    }
}

extern "C" void kernel_launch(void* const* d_in, const int* in_sizes, int n_in,
                              void* d_out, int out_size, void* d_ws, size_t ws_size,
                              hipStream_t stream){
    const float* Aq     = (const float*)d_in[0];   // [1024,768]
    const float* Bt     = (const float*)d_in[1];   // [200000,768]
    const int*   labels = (const int*)d_in[2];     // [200000]
    float* out = (float*)d_out;

    unsigned* rowMaxBits = (unsigned*)d_ws;                 // 1024 u32
    int*      counts     = (int*)(rowMaxBits + MQ);         // 1024 i32
    int*      cands      = (int*)(counts + MQ);             // 1024*1024 i32

    hipLaunchKernelGGL(init_kernel, dim3(4), dim3(256), 0, stream, rowMaxBits, counts);
    hipLaunchKernelGGL(gemm_collect_kernel, dim3(8, (NTRAIN + 127) / 128), dim3(256), 0, stream,
                       Aq, Bt, rowMaxBits, counts, cands);
    hipLaunchKernelGGL(rescore_output_kernel, dim3(MQ), dim3(256), 0, stream,
                       Aq, Bt, labels, counts, cands, out);
}